// Round 1
// baseline (9.792 us; speedup 1.0000x reference)
//
#include <hip/hip_runtime.h>

// C4MoEVM: per-element 7-way "MoE VM".
// Gates are numerically one-hot (scale-20 silu eq-gates at integer distances:
// on = sigmoid(20)^2 ~ 1-4e-9, off ~ 2e-9), softmax table lookups with scale
// 1000 are EXACTLY one-hot in fp32 (exp(-1000) underflows). So the reference
// reduces to: switch(opcode) { add, sub, a*b, a&b, a|b, a^b, recip(b) }.
// recip replicates the reference path: e = floor(log2(b))+1 (exact via clz on
// the integer value of b), temp = b*2^-e in [0.5,1), y0 = recip_val[(temp-0.5)*256]
// (exact integer index for all integer b in [1,15]), two fp32 Newton steps,
// scale by 2^-e.

__device__ __forceinline__ float compute_one(float av, float bv, int op,
                                             const float* __restrict__ recip_val) {
    int ia = (int)(av + 0.5f);   // a,b are exact integer-valued floats in [1,15]
    int ib = (int)(bv + 0.5f);
    float r;
    if (op == 0) {
        r = av + bv;
    } else if (op == 1) {
        r = av - bv;
    } else if (op == 2) {
        r = (float)(ia * ib);                 // == round(silu(a)*b + silu(-a)*(-b))
    } else if (op == 3) {
        r = (float)(ia & ib);
    } else if (op == 4) {
        r = (float)(ia | ib);
    } else if (op == 5) {
        r = (float)(ia ^ ib);
    } else {
        // reciprocal expert
        int e = 32 - __clz(ib);               // floor(log2(b)) + 1, exact
        float temp = __builtin_ldexpf(bv, -e);          // in [0.5, 1)
        int idx = (int)((temp - 0.5f) * 256.0f + 0.5f); // exact integer for our inputs
        float y = recip_val[idx];             // same table as reference
        y = y * (2.0f - temp * y);            // Newton 1
        y = y * (2.0f - temp * y);            // Newton 2
        r = __builtin_ldexpf(y, -e);
    }
    return r;
}

__global__ __launch_bounds__(256) void c4moe_kernel(
    const float* __restrict__ a, const float* __restrict__ b,
    const int* __restrict__ opcode, const float* __restrict__ recip_val,
    float* __restrict__ out, int n)
{
    int t = blockIdx.x * blockDim.x + threadIdx.x;
    int i = t * 4;
    if (i + 4 <= n) {
        // vectorized path: 16B/lane coalesced loads
        float4 av = *reinterpret_cast<const float4*>(a + i);
        float4 bv = *reinterpret_cast<const float4*>(b + i);
        int4   ov = *reinterpret_cast<const int4*>(opcode + i);
        float4 r;
        r.x = compute_one(av.x, bv.x, ov.x, recip_val);
        r.y = compute_one(av.y, bv.y, ov.y, recip_val);
        r.z = compute_one(av.z, bv.z, ov.z, recip_val);
        r.w = compute_one(av.w, bv.w, ov.w, recip_val);
        *reinterpret_cast<float4*>(out + i) = r;
    } else {
        for (int j = i; j < n; ++j)
            out[j] = compute_one(a[j], b[j], opcode[j], recip_val);
    }
}

extern "C" void kernel_launch(void* const* d_in, const int* in_sizes, int n_in,
                              void* d_out, int out_size, void* d_ws, size_t ws_size,
                              hipStream_t stream) {
    const float* a         = (const float*)d_in[0];
    const float* b         = (const float*)d_in[1];
    const int*   opcode    = (const int*)d_in[2];
    // d_in[3..5] = and/or/xor tables (unneeded: integer bit-ops are exact)
    const float* recip_val = (const float*)d_in[6];
    float* out = (float*)d_out;

    int n = in_sizes[0];
    int n4 = (n + 3) / 4;
    int block = 256;
    int grid = (n4 + block - 1) / block;
    c4moe_kernel<<<grid, block, 0, stream>>>(a, b, opcode, recip_val, out, n);
}

// Round 2
// 9.789 us; speedup vs baseline: 1.0004x; 1.0004x over previous
//
#include <hip/hip_runtime.h>

// C4MoEVM: per-element 7-way "MoE VM", fully collapsed + branchless.
//
// The reference's gates are numerically one-hot (sigmoid(±20) saturates to
// 1/0 at ~2e-9) and the scale-1000 softmax lookups are EXACTLY one-hot in
// fp32 (exp(-1000) underflows). So: switch(opcode){add,sub,a*b,a&b,a|b,a^b,
// recip(b)}. a,b are exact integer-valued floats in [1,15]:
//   - a*b <= 225 is exact in fp32, no int mul needed
//   - reference recip = (8-bit table + 2 Newton steps) * 2^-e  ==  1/b to
//     ~1e-7 abs; v_rcp_f32 (1 ulp) is within the 4.5 absmax threshold by 7
//     orders of magnitude, so the table read (a dependent gather) is dropped.
//
// Branchless select (6 cndmasks) removes the 7-way exec-mask serialization:
// random opcodes made every wave execute every arm. float2/thread doubles
// wave count vs float4/thread (2048 waves -> 8/CU) for latency hiding; total
// traffic is only 4 MB so the kernel is latency/launch-bound, not BW-bound.

__device__ __forceinline__ float compute_one(float av, float bv, int op) {
    int ia = (int)av;                 // exact: inputs are integer-valued
    int ib = (int)bv;
    float r0 = av + bv;
    float r1 = av - bv;
    float r2 = av * bv;               // exact for |a*b| <= 225
    float r3 = (float)(ia & ib);
    float r4 = (float)(ia | ib);
    float r5 = (float)(ia ^ ib);
    float r6 = __builtin_amdgcn_rcpf(bv);
    float r = (op == 0) ? r0
            : (op == 1) ? r1
            : (op == 2) ? r2
            : (op == 3) ? r3
            : (op == 4) ? r4
            : (op == 5) ? r5
            :             r6;
    return r;
}

__global__ __launch_bounds__(256) void c4moe_kernel(
    const float* __restrict__ a, const float* __restrict__ b,
    const int* __restrict__ opcode, float* __restrict__ out, int n)
{
    int t = blockIdx.x * blockDim.x + threadIdx.x;
    int i = t * 2;
    if (i + 2 <= n) {
        float2 av = *reinterpret_cast<const float2*>(a + i);
        float2 bv = *reinterpret_cast<const float2*>(b + i);
        int2   ov = *reinterpret_cast<const int2*>(opcode + i);
        float2 r;
        r.x = compute_one(av.x, bv.x, ov.x);
        r.y = compute_one(av.y, bv.y, ov.y);
        *reinterpret_cast<float2*>(out + i) = r;
    } else {
        for (int j = i; j < n; ++j)
            out[j] = compute_one(a[j], b[j], opcode[j]);
    }
}

extern "C" void kernel_launch(void* const* d_in, const int* in_sizes, int n_in,
                              void* d_out, int out_size, void* d_ws, size_t ws_size,
                              hipStream_t stream) {
    const float* a      = (const float*)d_in[0];
    const float* b      = (const float*)d_in[1];
    const int*   opcode = (const int*)d_in[2];
    // d_in[3..6] (bitwise tables, recip table) unneeded: exact int ops + rcp
    float* out = (float*)d_out;

    int n = in_sizes[0];
    int n2 = (n + 1) / 2;
    int block = 256;
    int grid = (n2 + block - 1) / block;
    c4moe_kernel<<<grid, block, 0, stream>>>(a, b, opcode, out, n);
}